// Round 7
// baseline (178.350 us; speedup 1.0000x reference)
//
#include <hip/hip_runtime.h>
#include <hip/hip_bf16.h>
#include <math.h>

#define B_   4
#define T_   2048
#define KDIM 1024
#define H_   16
#define D_   64
#define BH_  (B_*H_)      // 64
#define M_   (B_*T_)      // 8192
#define NKT  (KDIM/64)    // 16 K-tiles

typedef __bf16 bf16;
typedef __bf16 bf16x8 __attribute__((ext_vector_type(8)));
typedef __bf16 bf16x4 __attribute__((ext_vector_type(4)));
typedef float  f32x4  __attribute__((ext_vector_type(4)));
typedef float  f32x16 __attribute__((ext_vector_type(16)));
typedef unsigned int u32;
typedef u32 u32x4 __attribute__((ext_vector_type(4)));

static __device__ __forceinline__ f32x4 mfma16(bf16x8 a, bf16x8 b, f32x4 c) {
    return __builtin_amdgcn_mfma_f32_16x16x32_bf16(a, b, c, 0, 0, 0);
}
static __device__ __forceinline__ f32x16 mfma32(bf16x8 a, bf16x8 b, f32x16 c) {
    return __builtin_amdgcn_mfma_f32_32x32x16_bf16(a, b, c, 0, 0, 0);
}
static __device__ __forceinline__ float exp2_fast(float x) {
    float r; asm("v_exp_f32 %0, %1" : "=v"(r) : "v"(x)); return r;
}

// ---------------- merged fp32 -> bf16 conversion (one launch) ----------------
__global__ void cvt_all(const float* __restrict__ x,  const float* __restrict__ Wq,
                        const float* __restrict__ Wk, const float* __restrict__ Wv,
                        bf16* __restrict__ dst) {
    int i = blockIdx.x * blockDim.x + threadIdx.x;
    const int NX = M_*KDIM/4, NW = KDIM*KDIM/4;
    const float* src;
    int j;
    if (i < NX)                { src = x;  j = i; }
    else if (i < NX + NW)      { src = Wq; j = i - NX; }
    else if (i < NX + 2*NW)    { src = Wk; j = i - NX - NW; }
    else                       { src = Wv; j = i - NX - 2*NW; }
    float4 v = reinterpret_cast<const float4*>(src)[j];
    bf16x4 o;
    o.x = (bf16)v.x; o.y = (bf16)v.y; o.z = (bf16)v.z; o.w = (bf16)v.w;
    reinterpret_cast<bf16x4*>(dst)[i] = o;
}

// ---------------- fused QKV GEMM, 256x256 tile, 8-phase schedule ----------------
// 8 waves (2M x 4N), per-wave 128x64 output, BK=64, LDS 128 KB (2-slot A + 2-slot B).
// Per K-tile: 4 quadrant-phases {12 ds_read, 2 stage, [wait], bar, lgkm0, 16 MFMA, bar}.
// Stage order per group (tile t+1): [A0,A2 | B0,B1 | B2,B3 | A1,A3]; mid vmcnt(4), end vmcnt(2).
__global__ __launch_bounds__(512) void proj_gemm8p(
    const bf16* __restrict__ xb, const bf16* __restrict__ Wflat,
    bf16* __restrict__ Qb, bf16* __restrict__ Kb, bf16* __restrict__ Vtb)
{
    __shared__ __align__(16) char As[2*32768];   // [slot][256][64] bf16, XOR-swizzled rows
    __shared__ __align__(16) char Bs[2*32768];

    const int tid  = threadIdx.x;
    const int wid  = tid >> 6;
    const int lane = tid & 63;
    const int l15  = lane & 15, l4 = lane >> 4;
    const int wm   = wid >> 2;     // 0..1  (M half)
    const int wn   = wid & 3;      // 0..3  (N quarter)

    // L2-tiled XCD mapping: 384 = 8 XCDs x 48; concurrent ~32/XCD = 4 mblk x 8 nblk
    const int orig = blockIdx.x;
    const int xcd  = orig & 7;
    const int idx  = orig >> 3;                 // 0..47
    const int mblk = xcd * 4 + (idx & 3);       // 0..31
    const int nblk = idx >> 2;                  // 0..11
    const int row0 = mblk * 256, col0 = nblk * 256;

    // staging sources (pre-swizzled): chunk c = 64 rows; thread covers row c*64+(tid>>3), colb (tid&7)*16
    const int srow  = tid >> 3;
    const int scolb = (tid & 7) * 16;
    const int scbs  = scolb ^ ((srow & 7) << 4);      // (row&7)==(srow&7) since c*64 % 8 == 0
    const bf16* aS[4]; const bf16* bS[4];
#pragma unroll
    for (int c = 0; c < 4; ++c) {
        aS[c] = xb    + (size_t)(row0 + c*64 + srow)*KDIM + (scbs >> 1);
        bS[c] = Wflat + (size_t)(col0 + c*64 + srow)*KDIM + (scbs >> 1);
    }

    auto stA = [&](int kt, int c) {
        if (kt >= NKT) return;
        char* d = As + ((kt & 1)*32768 + c*8192 + wid*1024);     // wave-uniform base
        __builtin_amdgcn_global_load_lds(
            (const __attribute__((address_space(1))) void*)(aS[c] + kt*64),
            (__attribute__((address_space(3))) void*)d, 16, 0, 0);
    };
    auto stB = [&](int kt, int c) {
        if (kt >= NKT) return;
        char* d = Bs + ((kt & 1)*32768 + c*8192 + wid*1024);
        __builtin_amdgcn_global_load_lds(
            (const __attribute__((address_space(1))) void*)(bS[c] + kt*64),
            (__attribute__((address_space(3))) void*)d, 16, 0, 0);
    };

    f32x4 acc[8][4] = {};
    const int sw = (l15 & 7) << 4;

#define PHASE(MQ, NQ, STAGES, WAITS) do {                                              \
    bf16x8 af_[2][4]; bf16x8 bf_[2][2];                                                \
    _Pragma("unroll")                                                                  \
    for (int kk = 0; kk < 2; ++kk) {                                                   \
        const int cbk = (kk*64 + l4*16) ^ sw;                                          \
        _Pragma("unroll")                                                              \
        for (int m = 0; m < 4; ++m)                                                    \
            af_[kk][m] = *reinterpret_cast<const bf16x8*>(                             \
                Ap + (wm*128 + (MQ)*64 + m*16 + l15)*128 + cbk);                       \
        _Pragma("unroll")                                                              \
        for (int n = 0; n < 2; ++n)                                                    \
            bf_[kk][n] = *reinterpret_cast<const bf16x8*>(                             \
                Bp + (wn*64 + (NQ)*32 + n*16 + l15)*128 + cbk);                        \
    }                                                                                  \
    STAGES;                                                                            \
    WAITS;                                                                             \
    __builtin_amdgcn_s_barrier();                                                      \
    __builtin_amdgcn_sched_barrier(0);                                                 \
    asm volatile("s_waitcnt lgkmcnt(0)" ::: "memory");                                 \
    __builtin_amdgcn_sched_barrier(0);                                                 \
    __builtin_amdgcn_s_setprio(1);                                                     \
    _Pragma("unroll")                                                                  \
    for (int kk = 0; kk < 2; ++kk)                                                     \
        _Pragma("unroll")                                                              \
        for (int m = 0; m < 4; ++m)                                                    \
            _Pragma("unroll")                                                          \
            for (int n = 0; n < 2; ++n)                                                \
                acc[(MQ)*4+m][(NQ)*2+n] =                                              \
                    mfma16(af_[kk][m], bf_[kk][n], acc[(MQ)*4+m][(NQ)*2+n]);           \
    __builtin_amdgcn_s_setprio(0);                                                     \
    __builtin_amdgcn_s_barrier();                                                      \
    __builtin_amdgcn_sched_barrier(0);                                                 \
} while (0)

    // prologue: tile 0 fully staged, drained once
#pragma unroll
    for (int c = 0; c < 4; ++c) { stA(0, c); stB(0, c); }
    asm volatile("s_waitcnt vmcnt(0)" ::: "memory");
    __builtin_amdgcn_sched_barrier(0);
    __builtin_amdgcn_s_barrier();

    for (int t = 0; t < NKT; ++t) {
        const char* Ap = As + (t & 1)*32768;
        const char* Bp = Bs + (t & 1)*32768;
        const bool more = (t < NKT - 1);

        // phase 0 (mq0,nq0): stage A0,A2 of t+1
        PHASE(0, 0, { stA(t+1, 0); stA(t+1, 2); }, (void)0);
        // phase 1 (mq0,nq1): stage B0,B1; MID wait -> tile t's A1,A3 landed (4 newer in flight)
        PHASE(0, 1, { stB(t+1, 0); stB(t+1, 1); },
              { if (more) { asm volatile("s_waitcnt vmcnt(4)" ::: "memory"); }
                else      { asm volatile("s_waitcnt vmcnt(0)" ::: "memory"); }
                __builtin_amdgcn_sched_barrier(0); });
        // phase 2 (mq1,nq0): stage B2,B3
        PHASE(1, 0, { stB(t+1, 2); stB(t+1, 3); }, (void)0);
        // phase 3 (mq1,nq1): stage A1,A3; END wait -> tile t+1 idx0..5 landed (A1,A3 in flight)
        PHASE(1, 1, { stA(t+1, 1); stA(t+1, 3); },
              { if (more) { asm volatile("s_waitcnt vmcnt(2)" ::: "memory");
                            __builtin_amdgcn_sched_barrier(0); } });
    }
#undef PHASE

    // ---- epilogue: C/D layout col=l15, row=l4*4+r ----
#pragma unroll
    for (int m = 0; m < 8; ++m)
#pragma unroll
        for (int n = 0; n < 4; ++n)
#pragma unroll
            for (int r = 0; r < 4; ++r) {
                int gi = row0 + wm*128 + m*16 + l4*4 + r;     // 0..8191
                int gj = col0 + wn*64  + n*16 + l15;          // 0..3071
                int wz  = gj >> 10;
                int gjw = gj & 1023;
                float v = acc[m][n][r];
                if (wz == 0) v *= 0.18033688011112042f;       // 0.125*log2(e) into Q
                bf16 o = (bf16)v;
                int bb = gi >> 11, tt = gi & (T_-1);
                int hh = gjw >> 6, dd = gjw & (D_-1);
                size_t bh = (size_t)bb*H_ + hh;
                if (wz == 0)      Qb [(bh*T_ + tt)*D_ + dd] = o;
                else if (wz == 1) Kb [(bh*T_ + tt)*D_ + dd] = o;
                else              Vtb[(bh*D_ + dd)*T_ + tt] = o;
            }
}

// ---------------- causal flash attention v3 (unchanged, proven) ----------------
__global__ __launch_bounds__(256) void flash_attn3(
    const bf16* __restrict__ Qb, const bf16* __restrict__ Kb,
    const bf16* __restrict__ Vtb, float* __restrict__ out)
{
    __shared__ __align__(16) char Ksm[8192];
    __shared__ __align__(16) char Vsm[8192];

    const int tid  = threadIdx.x;
    const int wid  = tid >> 6;
    const int lane = tid & 63;
    const int l31  = lane & 31;
    const int hi   = lane >> 5;

    const int orig = blockIdx.x;
    const int wg   = (orig & 7) * 128 + (orig >> 3);
    const int bh   = wg >> 4;
    const int qblk = (15 - (wg & 15)) * 128;
    const int q0   = qblk + wid * 32;
    const int q_abs = q0 + l31;

    const bf16* qp = Qb + ((size_t)bh*T_ + q_abs)*D_ + hi*8;
    bf16x8 qf[4];
#pragma unroll
    for (int j = 0; j < 4; ++j)
        qf[j] = *reinterpret_cast<const bf16x8*>(qp + j*16);

    const bf16* kbase = Kb  + (size_t)bh*T_*D_;
    const bf16* vbase = Vtb + (size_t)bh*D_*T_;

    f32x16 o0 = {}; f32x16 o1 = {};
    float lsum = 0.f;

    const int my_nt  = (q0 + 31) >> 6;
    const int blk_nt = qblk/64 + 1;
    const int tmaskb = q_abs - 4*hi;

    const int r0 = tid >> 3,          r1 = (tid + 256) >> 3;
    const int e0 = (tid & 7) * 8;
    const u32 lds0 = (u32)((r0*128 + e0*2) ^ ((r0 & 7) << 4));
    const u32 lds1 = (u32)((r1*128 + e0*2) ^ ((r1 & 7) << 4));

    u32x4 kr0, kr1, vr0, vr1;
    auto issue = [&](int nt) {
        kr0 = *reinterpret_cast<const u32x4*>(kbase + ((size_t)(nt*64 + r0))*D_ + e0);
        kr1 = *reinterpret_cast<const u32x4*>(kbase + ((size_t)(nt*64 + r1))*D_ + e0);
        vr0 = *reinterpret_cast<const u32x4*>(vbase + (size_t)r0*T_ + nt*64 + e0);
        vr1 = *reinterpret_cast<const u32x4*>(vbase + (size_t)r1*T_ + nt*64 + e0);
    };
    issue(0);

    auto subtile = [&](int s, int kvb_abs, bool maskit, bf16x8& pA, bf16x8& pB) {
        f32x16 sacc = {};
        const int row = s*32 + l31;
        const int swk = (row & 7) << 4;
#pragma unroll
        for (int j = 0; j < 4; ++j) {
            bf16x8 kf = *reinterpret_cast<const bf16x8*>(Ksm + ((row*128 + j*32 + hi*16) ^ swk));
            sacc = mfma32(kf, qf[j], sacc);
        }
        const int tlim = tmaskb - kvb_abs;
        float p[16];
#pragma unroll
        for (int r = 0; r < 16; ++r) {
            const int crow0 = (r & 3) + 8*(r >> 2);
            float sv = sacc[r];
            if (maskit) sv = (crow0 > tlim) ? -INFINITY : sv;
            p[r] = exp2_fast(sv);
        }
        {
            float a0 = p[0]+p[1],   a1 = p[2]+p[3],   a2 = p[4]+p[5],   a3 = p[6]+p[7];
            float a4 = p[8]+p[9],   a5 = p[10]+p[11], a6 = p[12]+p[13], a7 = p[14]+p[15];
            lsum += ((a0+a1) + (a2+a3)) + ((a4+a5) + (a6+a7));
        }
        u32 w[8];
#pragma unroll
        for (int i = 0; i < 8; ++i) {
            u32 wv;
            asm("v_cvt_pk_bf16_f32 %0, %1, %2" : "=v"(wv) : "v"(p[2*i]), "v"(p[2*i+1]));
            w[i] = wv;
        }
        u32 a0w = w[0], a2w = w[2];
        asm("v_permlane32_swap_b32 %0, %1" : "+v"(a0w), "+v"(a2w));
        u32 a1w = w[1], a3w = w[3];
        asm("v_permlane32_swap_b32 %0, %1" : "+v"(a1w), "+v"(a3w));
        u32 b0w = w[4], b2w = w[6];
        asm("v_permlane32_swap_b32 %0, %1" : "+v"(b0w), "+v"(b2w));
        u32 b1w = w[5], b3w = w[7];
        asm("v_permlane32_swap_b32 %0, %1" : "+v"(b1w), "+v"(b3w));
        u32x4 A0 = {a0w, a1w, a2w, a3w};
        u32x4 A1 = {b0w, b1w, b2w, b3w};
        pA = __builtin_bit_cast(bf16x8, A0);
        pB = __builtin_bit_cast(bf16x8, A1);
    };

    auto pv = [&](int ks, bf16x8 pf) {
        const int swv = (l31 & 7) << 4;
        const int colb = ks*32 + hi*16;
        bf16x8 v0 = *reinterpret_cast<const bf16x8*>(Vsm + ((l31*128 + colb) ^ swv));
        bf16x8 v1 = *reinterpret_cast<const bf16x8*>(Vsm + (((32 + l31)*128 + colb) ^ swv));
        o0 = mfma32(v0, pf, o0);
        o1 = mfma32(v1, pf, o1);
    };

    for (int nt = 0; nt <= blk_nt; ++nt) {
        __syncthreads();
        *reinterpret_cast<u32x4*>(Ksm + lds0) = kr0;
        *reinterpret_cast<u32x4*>(Ksm + lds1) = kr1;
        *reinterpret_cast<u32x4*>(Vsm + lds0) = vr0;
        *reinterpret_cast<u32x4*>(Vsm + lds1) = vr1;
        __syncthreads();
        if (nt < blk_nt) issue(nt + 1);

        if (nt <= my_nt) {
            const bool partial = (nt == my_nt);
            const int  nsub = (!partial || (q0 & 32)) ? 2 : 1;
            bf16x8 pA, pB;
            subtile(0, nt*64, partial, pA, pB);
            pv(0, pA);
            pv(1, pB);
            if (nsub == 2) {
                subtile(1, nt*64 + 32, partial, pA, pB);
                pv(2, pA);
                pv(3, pB);
            }
        }
    }

    lsum += __shfl_xor(lsum, 32);
    const float inv = 1.0f / lsum;
    const int bb = bh >> 4, hh = bh & 15;
    float* orow = out + ((size_t)bb*T_ + q_abs)*KDIM + hh*64 + hi*4;
#pragma unroll
    for (int g = 0; g < 4; ++g) {
        f32x4 v0, v1;
#pragma unroll
        for (int j = 0; j < 4; ++j) { v0[j] = o0[g*4+j]*inv; v1[j] = o1[g*4+j]*inv; }
        *reinterpret_cast<f32x4*>(orow + g*8)      = v0;
        *reinterpret_cast<f32x4*>(orow + 32 + g*8) = v1;
    }
}

extern "C" void kernel_launch(void* const* d_in, const int* in_sizes, int n_in,
                              void* d_out, int out_size, void* d_ws, size_t ws_size,
                              hipStream_t stream) {
    (void)in_sizes; (void)n_in; (void)out_size; (void)ws_size;
    const float* x  = (const float*)d_in[0];
    const float* Wq = (const float*)d_in[1];
    const float* Wk = (const float*)d_in[2];
    const float* Wv = (const float*)d_in[3];
    float* out = (float*)d_out;

    bf16* xb  = (bf16*)d_ws;
    bf16* Wb  = xb + (size_t)M_*KDIM;
    bf16* Qb  = Wb + (size_t)3*KDIM*KDIM;
    bf16* Kb  = Qb + (size_t)M_*KDIM;
    bf16* Vtb = Kb + (size_t)M_*KDIM;

    const int n4 = (M_*KDIM + 3*KDIM*KDIM) / 4;
    cvt_all<<<(n4 + 255)/256, 256, 0, stream>>>(x, Wq, Wk, Wv, xb);

    proj_gemm8p<<<dim3(384), 512, 0, stream>>>(xb, Wb, Qb, Kb, Vtb);
    flash_attn3<<<dim3(BH_*16), 256, 0, stream>>>(Qb, Kb, Vtb, out);
}

// Round 8
// 163.077 us; speedup vs baseline: 1.0937x; 1.0937x over previous
//
#include <hip/hip_runtime.h>
#include <hip/hip_bf16.h>
#include <math.h>

#define B_   4
#define T_   2048
#define KDIM 1024
#define H_   16
#define D_   64
#define BH_  (B_*H_)      // 64
#define M_   (B_*T_)      // 8192
#define NKT  (KDIM/64)    // 16 K-tiles

typedef __bf16 bf16;
typedef __bf16 bf16x8 __attribute__((ext_vector_type(8)));
typedef __bf16 bf16x4 __attribute__((ext_vector_type(4)));
typedef float  f32x4  __attribute__((ext_vector_type(4)));
typedef float  f32x16 __attribute__((ext_vector_type(16)));
typedef unsigned int u32;
typedef u32 u32x4 __attribute__((ext_vector_type(4)));

static __device__ __forceinline__ f32x4 mfma16(bf16x8 a, bf16x8 b, f32x4 c) {
    return __builtin_amdgcn_mfma_f32_16x16x32_bf16(a, b, c, 0, 0, 0);
}
static __device__ __forceinline__ f32x16 mfma32(bf16x8 a, bf16x8 b, f32x16 c) {
    return __builtin_amdgcn_mfma_f32_32x32x16_bf16(a, b, c, 0, 0, 0);
}
static __device__ __forceinline__ float exp2_fast(float x) {
    float r; asm("v_exp_f32 %0, %1" : "=v"(r) : "v"(x)); return r;
}

// ---------------- merged fp32 -> bf16 conversion (one launch) ----------------
__global__ void cvt_all(const float* __restrict__ x,  const float* __restrict__ Wq,
                        const float* __restrict__ Wk, const float* __restrict__ Wv,
                        bf16* __restrict__ dst) {
    int i = blockIdx.x * blockDim.x + threadIdx.x;
    const int NX = M_*KDIM/4, NW = KDIM*KDIM/4;
    const float* src;
    int j;
    if (i < NX)                { src = x;  j = i; }
    else if (i < NX + NW)      { src = Wq; j = i - NX; }
    else if (i < NX + 2*NW)    { src = Wk; j = i - NX - NW; }
    else                       { src = Wv; j = i - NX - 2*NW; }
    float4 v = reinterpret_cast<const float4*>(src)[j];
    bf16x4 o;
    o.x = (bf16)v.x; o.y = (bf16)v.y; o.z = (bf16)v.z; o.w = (bf16)v.w;
    reinterpret_cast<bf16x4*>(dst)[i] = o;
}

// ---------------- fused QKV GEMM: C[8192][3072] = x · Wflat^T ----------------
// m97 structure: 128x128 tile, BK=64, 4 waves (2x2), single-buffered LDS (32 KB),
// 2-barrier K-loop, global_load_lds width 16. Multi-block/CU (~4) provides the
// cross-block overlap that hides the stage/barrier stall (m114 mechanism).
// 3-bit XOR swizzle via pre-swizzled source (R5-verified: 0 bank conflicts).
// XCD map: each XCD owns 8 mblk (A panels L2-resident), sweeps nblk outer.
__global__ __launch_bounds__(256) void proj_gemm97(
    const bf16* __restrict__ xb, const bf16* __restrict__ Wflat,
    bf16* __restrict__ Qb, bf16* __restrict__ Kb, bf16* __restrict__ Vtb)
{
    __shared__ __align__(16) char Asm[128*128];   // [128 rows][128 B], rows XOR-swizzled
    __shared__ __align__(16) char Bsm[128*128];

    const int tid  = threadIdx.x;
    const int wid  = tid >> 6;
    const int lane = tid & 63;
    const int l15  = lane & 15, l4 = lane >> 4;
    const int wr = wid >> 1, wc = wid & 1;

    // XCD map: 1536 blocks = 8 XCDs x 192; per XCD mblk = xcd*8+(idx&7), nblk = idx>>3
    const int orig = blockIdx.x;
    const int xcd  = orig & 7;
    const int idx  = orig >> 3;                 // 0..191
    const int mblk = xcd * 8 + (idx & 7);       // 0..63
    const int nblk = idx >> 3;                  // 0..23
    const int row0 = mblk * 128, col0 = nblk * 128;

    // staging sources, pre-swizzled: LDS[r][cb] = G[r][cb ^ ((r&7)<<4)]
    const bf16* aS[4]; const bf16* bS[4];
#pragma unroll
    for (int q = 0; q < 4; ++q) {
        int c   = q*256 + tid;                  // 16B chunk 0..1023
        int rr  = c >> 3;                       // 0..127
        int cb  = (c & 7) * 16;
        int cbs = cb ^ ((rr & 7) << 4);
        aS[q] = xb    + (size_t)(row0 + rr)*KDIM + (cbs >> 1);
        bS[q] = Wflat + (size_t)(col0 + rr)*KDIM + (cbs >> 1);
    }

    f32x4 acc[4][4] = {};
    const int sw   = (l15 & 7) << 4;
    const int arow = (wr*64 + l15) * 128;
    const int brow = (wc*64 + l15) * 128;

    for (int kt = 0; kt < NKT; ++kt) {
        const int k0 = kt * 64;
        __syncthreads();                        // previous compute done reading LDS
#pragma unroll
        for (int q = 0; q < 4; ++q) {
            char* la = Asm + (q*256 + wid*64)*16;     // wave-uniform base
            __builtin_amdgcn_global_load_lds(
                (const __attribute__((address_space(1))) void*)(aS[q] + k0),
                (__attribute__((address_space(3))) void*)la, 16, 0, 0);
        }
#pragma unroll
        for (int q = 0; q < 4; ++q) {
            char* lb = Bsm + (q*256 + wid*64)*16;
            __builtin_amdgcn_global_load_lds(
                (const __attribute__((address_space(1))) void*)(bS[q] + k0),
                (__attribute__((address_space(3))) void*)lb, 16, 0, 0);
        }
        asm volatile("s_waitcnt vmcnt(0)" ::: "memory");
        __syncthreads();

#pragma unroll
        for (int kk = 0; kk < 2; ++kk) {
            const int cbk = (kk*64 + l4*16) ^ sw;
            bf16x8 af[4], bfr[4];
#pragma unroll
            for (int m = 0; m < 4; ++m)
                af[m] = *reinterpret_cast<const bf16x8*>(Asm + arow + m*2048 + cbk);
#pragma unroll
            for (int n = 0; n < 4; ++n)
                bfr[n] = *reinterpret_cast<const bf16x8*>(Bsm + brow + n*2048 + cbk);
#pragma unroll
            for (int m = 0; m < 4; ++m)
#pragma unroll
                for (int n = 0; n < 4; ++n)
                    acc[m][n] = mfma16(af[m], bfr[n], acc[m][n]);
        }
    }

    // ---- epilogue: C/D layout col=l15, row=l4*4+r ----
#pragma unroll
    for (int m = 0; m < 4; ++m)
#pragma unroll
        for (int n = 0; n < 4; ++n)
#pragma unroll
            for (int r = 0; r < 4; ++r) {
                int gi = row0 + wr*64 + m*16 + l4*4 + r;      // 0..8191
                int gj = col0 + wc*64 + n*16 + l15;           // 0..3071
                int wz  = gj >> 10;
                int gjw = gj & 1023;
                float v = acc[m][n][r];
                if (wz == 0) v *= 0.18033688011112042f;       // 0.125*log2(e) into Q
                bf16 o = (bf16)v;
                int bb = gi >> 11, tt = gi & (T_-1);
                int hh = gjw >> 6, dd = gjw & (D_-1);
                size_t bh = (size_t)bb*H_ + hh;
                if (wz == 0)      Qb [(bh*T_ + tt)*D_ + dd] = o;
                else if (wz == 1) Kb [(bh*T_ + tt)*D_ + dd] = o;
                else              Vtb[(bh*D_ + dd)*T_ + tt] = o;
            }
}

// ---------------- causal flash attention v3 (unchanged, proven) ----------------
__global__ __launch_bounds__(256) void flash_attn3(
    const bf16* __restrict__ Qb, const bf16* __restrict__ Kb,
    const bf16* __restrict__ Vtb, float* __restrict__ out)
{
    __shared__ __align__(16) char Ksm[8192];
    __shared__ __align__(16) char Vsm[8192];

    const int tid  = threadIdx.x;
    const int wid  = tid >> 6;
    const int lane = tid & 63;
    const int l31  = lane & 31;
    const int hi   = lane >> 5;

    const int orig = blockIdx.x;
    const int wg   = (orig & 7) * 128 + (orig >> 3);
    const int bh   = wg >> 4;
    const int qblk = (15 - (wg & 15)) * 128;
    const int q0   = qblk + wid * 32;
    const int q_abs = q0 + l31;

    const bf16* qp = Qb + ((size_t)bh*T_ + q_abs)*D_ + hi*8;
    bf16x8 qf[4];
#pragma unroll
    for (int j = 0; j < 4; ++j)
        qf[j] = *reinterpret_cast<const bf16x8*>(qp + j*16);

    const bf16* kbase = Kb  + (size_t)bh*T_*D_;
    const bf16* vbase = Vtb + (size_t)bh*D_*T_;

    f32x16 o0 = {}; f32x16 o1 = {};
    float lsum = 0.f;

    const int my_nt  = (q0 + 31) >> 6;
    const int blk_nt = qblk/64 + 1;
    const int tmaskb = q_abs - 4*hi;

    const int r0 = tid >> 3,          r1 = (tid + 256) >> 3;
    const int e0 = (tid & 7) * 8;
    const u32 lds0 = (u32)((r0*128 + e0*2) ^ ((r0 & 7) << 4));
    const u32 lds1 = (u32)((r1*128 + e0*2) ^ ((r1 & 7) << 4));

    u32x4 kr0, kr1, vr0, vr1;
    auto issue = [&](int nt) {
        kr0 = *reinterpret_cast<const u32x4*>(kbase + ((size_t)(nt*64 + r0))*D_ + e0);
        kr1 = *reinterpret_cast<const u32x4*>(kbase + ((size_t)(nt*64 + r1))*D_ + e0);
        vr0 = *reinterpret_cast<const u32x4*>(vbase + (size_t)r0*T_ + nt*64 + e0);
        vr1 = *reinterpret_cast<const u32x4*>(vbase + (size_t)r1*T_ + nt*64 + e0);
    };
    issue(0);

    auto subtile = [&](int s, int kvb_abs, bool maskit, bf16x8& pA, bf16x8& pB) {
        f32x16 sacc = {};
        const int row = s*32 + l31;
        const int swk = (row & 7) << 4;
#pragma unroll
        for (int j = 0; j < 4; ++j) {
            bf16x8 kf = *reinterpret_cast<const bf16x8*>(Ksm + ((row*128 + j*32 + hi*16) ^ swk));
            sacc = mfma32(kf, qf[j], sacc);
        }
        const int tlim = tmaskb - kvb_abs;
        float p[16];
#pragma unroll
        for (int r = 0; r < 16; ++r) {
            const int crow0 = (r & 3) + 8*(r >> 2);
            float sv = sacc[r];
            if (maskit) sv = (crow0 > tlim) ? -INFINITY : sv;
            p[r] = exp2_fast(sv);
        }
        {
            float a0 = p[0]+p[1],   a1 = p[2]+p[3],   a2 = p[4]+p[5],   a3 = p[6]+p[7];
            float a4 = p[8]+p[9],   a5 = p[10]+p[11], a6 = p[12]+p[13], a7 = p[14]+p[15];
            lsum += ((a0+a1) + (a2+a3)) + ((a4+a5) + (a6+a7));
        }
        u32 w[8];
#pragma unroll
        for (int i = 0; i < 8; ++i) {
            u32 wv;
            asm("v_cvt_pk_bf16_f32 %0, %1, %2" : "=v"(wv) : "v"(p[2*i]), "v"(p[2*i+1]));
            w[i] = wv;
        }
        u32 a0w = w[0], a2w = w[2];
        asm("v_permlane32_swap_b32 %0, %1" : "+v"(a0w), "+v"(a2w));
        u32 a1w = w[1], a3w = w[3];
        asm("v_permlane32_swap_b32 %0, %1" : "+v"(a1w), "+v"(a3w));
        u32 b0w = w[4], b2w = w[6];
        asm("v_permlane32_swap_b32 %0, %1" : "+v"(b0w), "+v"(b2w));
        u32 b1w = w[5], b3w = w[7];
        asm("v_permlane32_swap_b32 %0, %1" : "+v"(b1w), "+v"(b3w));
        u32x4 A0 = {a0w, a1w, a2w, a3w};
        u32x4 A1 = {b0w, b1w, b2w, b3w};
        pA = __builtin_bit_cast(bf16x8, A0);
        pB = __builtin_bit_cast(bf16x8, A1);
    };

    auto pv = [&](int ks, bf16x8 pf) {
        const int swv = (l31 & 7) << 4;
        const int colb = ks*32 + hi*16;
        bf16x8 v0 = *reinterpret_cast<const bf16x8*>(Vsm + ((l31*128 + colb) ^ swv));
        bf16x8 v1 = *reinterpret_cast<const bf16x8*>(Vsm + (((32 + l31)*128 + colb) ^ swv));
        o0 = mfma32(v0, pf, o0);
        o1 = mfma32(v1, pf, o1);
    };

    for (int nt = 0; nt <= blk_nt; ++nt) {
        __syncthreads();
        *reinterpret_cast<u32x4*>(Ksm + lds0) = kr0;
        *reinterpret_cast<u32x4*>(Ksm + lds1) = kr1;
        *reinterpret_cast<u32x4*>(Vsm + lds0) = vr0;
        *reinterpret_cast<u32x4*>(Vsm + lds1) = vr1;
        __syncthreads();
        if (nt < blk_nt) issue(nt + 1);

        if (nt <= my_nt) {
            const bool partial = (nt == my_nt);
            const int  nsub = (!partial || (q0 & 32)) ? 2 : 1;
            bf16x8 pA, pB;
            subtile(0, nt*64, partial, pA, pB);
            pv(0, pA);
            pv(1, pB);
            if (nsub == 2) {
                subtile(1, nt*64 + 32, partial, pA, pB);
                pv(2, pA);
                pv(3, pB);
            }
        }
    }

    lsum += __shfl_xor(lsum, 32);
    const float inv = 1.0f / lsum;
    const int bb = bh >> 4, hh = bh & 15;
    float* orow = out + ((size_t)bb*T_ + q_abs)*KDIM + hh*64 + hi*4;
#pragma unroll
    for (int g = 0; g < 4; ++g) {
        f32x4 v0, v1;
#pragma unroll
        for (int j = 0; j < 4; ++j) { v0[j] = o0[g*4+j]*inv; v1[j] = o1[g*4+j]*inv; }
        *reinterpret_cast<f32x4*>(orow + g*8)      = v0;
        *reinterpret_cast<f32x4*>(orow + 32 + g*8) = v1;
    }
}

extern "C" void kernel_launch(void* const* d_in, const int* in_sizes, int n_in,
                              void* d_out, int out_size, void* d_ws, size_t ws_size,
                              hipStream_t stream) {
    (void)in_sizes; (void)n_in; (void)out_size; (void)ws_size;
    const float* x  = (const float*)d_in[0];
    const float* Wq = (const float*)d_in[1];
    const float* Wk = (const float*)d_in[2];
    const float* Wv = (const float*)d_in[3];
    float* out = (float*)d_out;

    bf16* xb  = (bf16*)d_ws;
    bf16* Wb  = xb + (size_t)M_*KDIM;
    bf16* Qb  = Wb + (size_t)3*KDIM*KDIM;
    bf16* Kb  = Qb + (size_t)M_*KDIM;
    bf16* Vtb = Kb + (size_t)M_*KDIM;

    const int n4 = (M_*KDIM + 3*KDIM*KDIM) / 4;
    cvt_all<<<(n4 + 255)/256, 256, 0, stream>>>(x, Wq, Wk, Wv, xb);

    proj_gemm97<<<dim3(1536), 256, 0, stream>>>(xb, Wb, Qb, Kb, Vtb);
    flash_attn3<<<dim3(BH_*16), 256, 0, stream>>>(Qb, Kb, Vtb, out);
}

// Round 9
// 155.083 us; speedup vs baseline: 1.1500x; 1.0515x over previous
//
#include <hip/hip_runtime.h>
#include <hip/hip_bf16.h>
#include <math.h>

#define B_   4
#define T_   2048
#define KDIM 1024
#define H_   16
#define D_   64
#define BH_  (B_*H_)      // 64
#define M_   (B_*T_)      // 8192
#define NKT  (KDIM/64)    // 16 K-tiles

typedef __bf16 bf16;
typedef __bf16 bf16x8 __attribute__((ext_vector_type(8)));
typedef __bf16 bf16x4 __attribute__((ext_vector_type(4)));
typedef float  f32x4  __attribute__((ext_vector_type(4)));
typedef float  f32x16 __attribute__((ext_vector_type(16)));
typedef unsigned int u32;
typedef u32 u32x4 __attribute__((ext_vector_type(4)));

static __device__ __forceinline__ f32x4 mfma16(bf16x8 a, bf16x8 b, f32x4 c) {
    return __builtin_amdgcn_mfma_f32_16x16x32_bf16(a, b, c, 0, 0, 0);
}
static __device__ __forceinline__ f32x16 mfma32(bf16x8 a, bf16x8 b, f32x16 c) {
    return __builtin_amdgcn_mfma_f32_32x32x16_bf16(a, b, c, 0, 0, 0);
}
static __device__ __forceinline__ float exp2_fast(float x) {
    float r; asm("v_exp_f32 %0, %1" : "=v"(r) : "v"(x)); return r;
}

// ---------------- merged fp32 -> bf16 conversion (one launch) ----------------
__global__ void cvt_all(const float* __restrict__ x,  const float* __restrict__ Wq,
                        const float* __restrict__ Wk, const float* __restrict__ Wv,
                        bf16* __restrict__ dst) {
    int i = blockIdx.x * blockDim.x + threadIdx.x;
    const int NX = M_*KDIM/4, NW = KDIM*KDIM/4;
    const float* src;
    int j;
    if (i < NX)                { src = x;  j = i; }
    else if (i < NX + NW)      { src = Wq; j = i - NX; }
    else if (i < NX + 2*NW)    { src = Wk; j = i - NX - NW; }
    else                       { src = Wv; j = i - NX - 2*NW; }
    float4 v = reinterpret_cast<const float4*>(src)[j];
    bf16x4 o;
    o.x = (bf16)v.x; o.y = (bf16)v.y; o.z = (bf16)v.z; o.w = (bf16)v.w;
    reinterpret_cast<bf16x4*>(dst)[i] = o;
}

// ---------------- fused QKV GEMM: C[8192][3072] = x · Wflat^T ----------------
// 128x128 tile, BK=64, 4 waves (2x2). Double-buffered LDS (64 KB -> 2 blocks/CU,
// m114 cross-block hiding) + R5's counted-vmcnt 2-barrier schedule (never full-drain
// mid-loop). 3-bit XOR swizzle via pre-swizzled source (0 conflicts, R5-verified).
// XCD map: each XCD owns 8 mblk (A panels L2-resident), sweeps nblk outer.
__global__ __launch_bounds__(256) void proj_gemm_db(
    const bf16* __restrict__ xb, const bf16* __restrict__ Wflat,
    bf16* __restrict__ Qb, bf16* __restrict__ Kb, bf16* __restrict__ Vtb)
{
    __shared__ __align__(16) char As[2][16384];   // [slot][128 rows][128 B], XOR-swizzled
    __shared__ __align__(16) char Bs[2][16384];

    const int tid  = threadIdx.x;
    const int wid  = tid >> 6;
    const int lane = tid & 63;
    const int l15  = lane & 15, l4 = lane >> 4;
    const int wr = wid >> 1, wc = wid & 1;

    // XCD map: 1536 blocks = 8 XCDs x 192; per XCD mblk = xcd*8+(idx&7), nblk = idx>>3
    const int orig = blockIdx.x;
    const int xcd  = orig & 7;
    const int idx  = orig >> 3;                 // 0..191
    const int mblk = xcd * 8 + (idx & 7);       // 0..63
    const int nblk = idx >> 3;                  // 0..23
    const int row0 = mblk * 128, col0 = nblk * 128;

    // staging sources, pre-swizzled: LDS[r][cb] = G[r][cb ^ ((r&7)<<4)]
    const bf16* aS[4]; const bf16* bS[4];
#pragma unroll
    for (int q = 0; q < 4; ++q) {
        int c   = q*256 + tid;                  // 16B chunk 0..1023
        int rr  = c >> 3;                       // 0..127
        int cb  = (c & 7) * 16;
        int cbs = cb ^ ((rr & 7) << 4);
        aS[q] = xb    + (size_t)(row0 + rr)*KDIM + (cbs >> 1);
        bS[q] = Wflat + (size_t)(col0 + rr)*KDIM + (cbs >> 1);
    }

    auto stage = [&](int kt, int buf) {
        if (kt >= NKT) return;
        const int k0 = kt * 64;
#pragma unroll
        for (int q = 0; q < 4; ++q) {
            char* la = As[buf] + (q*256 + wid*64)*16;     // wave-uniform base
            __builtin_amdgcn_global_load_lds(
                (const __attribute__((address_space(1))) void*)(aS[q] + k0),
                (__attribute__((address_space(3))) void*)la, 16, 0, 0);
        }
#pragma unroll
        for (int q = 0; q < 4; ++q) {
            char* lb = Bs[buf] + (q*256 + wid*64)*16;
            __builtin_amdgcn_global_load_lds(
                (const __attribute__((address_space(1))) void*)(bS[q] + k0),
                (__attribute__((address_space(3))) void*)lb, 16, 0, 0);
        }
    };

    f32x4 acc[4][4] = {};
    const int sw   = (l15 & 7) << 4;
    const int arow = (wr*64 + l15) * 128;
    const int brow = (wc*64 + l15) * 128;

    // prologue: tiles 0,1 into slots 0,1 (16 loads outstanding)
    stage(0, 0);
    stage(1, 1);

    for (int t = 0; t < NKT; ++t) {
        const int bt = t & 1;
        if (t + 1 < NKT) {
            asm volatile("s_waitcnt vmcnt(8)" ::: "memory");   // tile t landed; t+1 in flight
        } else {
            asm volatile("s_waitcnt vmcnt(0)" ::: "memory");   // last tile
        }
        __builtin_amdgcn_sched_barrier(0);
        __builtin_amdgcn_s_barrier();
        __builtin_amdgcn_sched_barrier(0);

        const char* Ap = As[bt];
        const char* Bp = Bs[bt];
#pragma unroll
        for (int kk = 0; kk < 2; ++kk) {
            const int cbk = (kk*64 + l4*16) ^ sw;
            bf16x8 af[4], bfr[4];
#pragma unroll
            for (int m = 0; m < 4; ++m)
                af[m] = *reinterpret_cast<const bf16x8*>(Ap + arow + m*2048 + cbk);
#pragma unroll
            for (int n = 0; n < 4; ++n)
                bfr[n] = *reinterpret_cast<const bf16x8*>(Bp + brow + n*2048 + cbk);
            __builtin_amdgcn_s_setprio(1);
#pragma unroll
            for (int m = 0; m < 4; ++m)
#pragma unroll
                for (int n = 0; n < 4; ++n)
                    acc[m][n] = mfma16(af[m], bfr[n], acc[m][n]);
            __builtin_amdgcn_s_setprio(0);
        }

        if (t + 2 < NKT) {
            asm volatile("s_waitcnt lgkmcnt(0)" ::: "memory"); // this block's reads of bt retired
            __builtin_amdgcn_sched_barrier(0);
            __builtin_amdgcn_s_barrier();                      // ALL waves' reads retired
            __builtin_amdgcn_sched_barrier(0);
            stage(t + 2, bt);                                  // refill freed slot
        }
    }

    // ---- epilogue: C/D layout col=l15, row=l4*4+r ----
#pragma unroll
    for (int m = 0; m < 4; ++m)
#pragma unroll
        for (int n = 0; n < 4; ++n)
#pragma unroll
            for (int r = 0; r < 4; ++r) {
                int gi = row0 + wr*64 + m*16 + l4*4 + r;      // 0..8191
                int gj = col0 + wc*64 + n*16 + l15;           // 0..3071
                int wz  = gj >> 10;
                int gjw = gj & 1023;
                float v = acc[m][n][r];
                if (wz == 0) v *= 0.18033688011112042f;       // 0.125*log2(e) into Q
                bf16 o = (bf16)v;
                int bb = gi >> 11, tt = gi & (T_-1);
                int hh = gjw >> 6, dd = gjw & (D_-1);
                size_t bh = (size_t)bb*H_ + hh;
                if (wz == 0)      Qb [(bh*T_ + tt)*D_ + dd] = o;
                else if (wz == 1) Kb [(bh*T_ + tt)*D_ + dd] = o;
                else              Vtb[(bh*D_ + dd)*T_ + tt] = o;
            }
}

// ---------------- causal flash attention v3 (unchanged, proven) ----------------
__global__ __launch_bounds__(256) void flash_attn3(
    const bf16* __restrict__ Qb, const bf16* __restrict__ Kb,
    const bf16* __restrict__ Vtb, float* __restrict__ out)
{
    __shared__ __align__(16) char Ksm[8192];
    __shared__ __align__(16) char Vsm[8192];

    const int tid  = threadIdx.x;
    const int wid  = tid >> 6;
    const int lane = tid & 63;
    const int l31  = lane & 31;
    const int hi   = lane >> 5;

    const int orig = blockIdx.x;
    const int wg   = (orig & 7) * 128 + (orig >> 3);
    const int bh   = wg >> 4;
    const int qblk = (15 - (wg & 15)) * 128;
    const int q0   = qblk + wid * 32;
    const int q_abs = q0 + l31;

    const bf16* qp = Qb + ((size_t)bh*T_ + q_abs)*D_ + hi*8;
    bf16x8 qf[4];
#pragma unroll
    for (int j = 0; j < 4; ++j)
        qf[j] = *reinterpret_cast<const bf16x8*>(qp + j*16);

    const bf16* kbase = Kb  + (size_t)bh*T_*D_;
    const bf16* vbase = Vtb + (size_t)bh*D_*T_;

    f32x16 o0 = {}; f32x16 o1 = {};
    float lsum = 0.f;

    const int my_nt  = (q0 + 31) >> 6;
    const int blk_nt = qblk/64 + 1;
    const int tmaskb = q_abs - 4*hi;

    const int r0 = tid >> 3,          r1 = (tid + 256) >> 3;
    const int e0 = (tid & 7) * 8;
    const u32 lds0 = (u32)((r0*128 + e0*2) ^ ((r0 & 7) << 4));
    const u32 lds1 = (u32)((r1*128 + e0*2) ^ ((r1 & 7) << 4));

    u32x4 kr0, kr1, vr0, vr1;
    auto issue = [&](int nt) {
        kr0 = *reinterpret_cast<const u32x4*>(kbase + ((size_t)(nt*64 + r0))*D_ + e0);
        kr1 = *reinterpret_cast<const u32x4*>(kbase + ((size_t)(nt*64 + r1))*D_ + e0);
        vr0 = *reinterpret_cast<const u32x4*>(vbase + (size_t)r0*T_ + nt*64 + e0);
        vr1 = *reinterpret_cast<const u32x4*>(vbase + (size_t)r1*T_ + nt*64 + e0);
    };
    issue(0);

    auto subtile = [&](int s, int kvb_abs, bool maskit, bf16x8& pA, bf16x8& pB) {
        f32x16 sacc = {};
        const int row = s*32 + l31;
        const int swk = (row & 7) << 4;
#pragma unroll
        for (int j = 0; j < 4; ++j) {
            bf16x8 kf = *reinterpret_cast<const bf16x8*>(Ksm + ((row*128 + j*32 + hi*16) ^ swk));
            sacc = mfma32(kf, qf[j], sacc);
        }
        const int tlim = tmaskb - kvb_abs;
        float p[16];
#pragma unroll
        for (int r = 0; r < 16; ++r) {
            const int crow0 = (r & 3) + 8*(r >> 2);
            float sv = sacc[r];
            if (maskit) sv = (crow0 > tlim) ? -INFINITY : sv;
            p[r] = exp2_fast(sv);
        }
        {
            float a0 = p[0]+p[1],   a1 = p[2]+p[3],   a2 = p[4]+p[5],   a3 = p[6]+p[7];
            float a4 = p[8]+p[9],   a5 = p[10]+p[11], a6 = p[12]+p[13], a7 = p[14]+p[15];
            lsum += ((a0+a1) + (a2+a3)) + ((a4+a5) + (a6+a7));
        }
        u32 w[8];
#pragma unroll
        for (int i = 0; i < 8; ++i) {
            u32 wv;
            asm("v_cvt_pk_bf16_f32 %0, %1, %2" : "=v"(wv) : "v"(p[2*i]), "v"(p[2*i+1]));
            w[i] = wv;
        }
        u32 a0w = w[0], a2w = w[2];
        asm("v_permlane32_swap_b32 %0, %1" : "+v"(a0w), "+v"(a2w));
        u32 a1w = w[1], a3w = w[3];
        asm("v_permlane32_swap_b32 %0, %1" : "+v"(a1w), "+v"(a3w));
        u32 b0w = w[4], b2w = w[6];
        asm("v_permlane32_swap_b32 %0, %1" : "+v"(b0w), "+v"(b2w));
        u32 b1w = w[5], b3w = w[7];
        asm("v_permlane32_swap_b32 %0, %1" : "+v"(b1w), "+v"(b3w));
        u32x4 A0 = {a0w, a1w, a2w, a3w};
        u32x4 A1 = {b0w, b1w, b2w, b3w};
        pA = __builtin_bit_cast(bf16x8, A0);
        pB = __builtin_bit_cast(bf16x8, A1);
    };

    auto pv = [&](int ks, bf16x8 pf) {
        const int swv = (l31 & 7) << 4;
        const int colb = ks*32 + hi*16;
        bf16x8 v0 = *reinterpret_cast<const bf16x8*>(Vsm + ((l31*128 + colb) ^ swv));
        bf16x8 v1 = *reinterpret_cast<const bf16x8*>(Vsm + (((32 + l31)*128 + colb) ^ swv));
        o0 = mfma32(v0, pf, o0);
        o1 = mfma32(v1, pf, o1);
    };

    for (int nt = 0; nt <= blk_nt; ++nt) {
        __syncthreads();
        *reinterpret_cast<u32x4*>(Ksm + lds0) = kr0;
        *reinterpret_cast<u32x4*>(Ksm + lds1) = kr1;
        *reinterpret_cast<u32x4*>(Vsm + lds0) = vr0;
        *reinterpret_cast<u32x4*>(Vsm + lds1) = vr1;
        __syncthreads();
        if (nt < blk_nt) issue(nt + 1);

        if (nt <= my_nt) {
            const bool partial = (nt == my_nt);
            const int  nsub = (!partial || (q0 & 32)) ? 2 : 1;
            bf16x8 pA, pB;
            subtile(0, nt*64, partial, pA, pB);
            pv(0, pA);
            pv(1, pB);
            if (nsub == 2) {
                subtile(1, nt*64 + 32, partial, pA, pB);
                pv(2, pA);
                pv(3, pB);
            }
        }
    }

    lsum += __shfl_xor(lsum, 32);
    const float inv = 1.0f / lsum;
    const int bb = bh >> 4, hh = bh & 15;
    float* orow = out + ((size_t)bb*T_ + q_abs)*KDIM + hh*64 + hi*4;
#pragma unroll
    for (int g = 0; g < 4; ++g) {
        f32x4 v0, v1;
#pragma unroll
        for (int j = 0; j < 4; ++j) { v0[j] = o0[g*4+j]*inv; v1[j] = o1[g*4+j]*inv; }
        *reinterpret_cast<f32x4*>(orow + g*8)      = v0;
        *reinterpret_cast<f32x4*>(orow + 32 + g*8) = v1;
    }
}

extern "C" void kernel_launch(void* const* d_in, const int* in_sizes, int n_in,
                              void* d_out, int out_size, void* d_ws, size_t ws_size,
                              hipStream_t stream) {
    (void)in_sizes; (void)n_in; (void)out_size; (void)ws_size;
    const float* x  = (const float*)d_in[0];
    const float* Wq = (const float*)d_in[1];
    const float* Wk = (const float*)d_in[2];
    const float* Wv = (const float*)d_in[3];
    float* out = (float*)d_out;

    bf16* xb  = (bf16*)d_ws;
    bf16* Wb  = xb + (size_t)M_*KDIM;
    bf16* Qb  = Wb + (size_t)3*KDIM*KDIM;
    bf16* Kb  = Qb + (size_t)M_*KDIM;
    bf16* Vtb = Kb + (size_t)M_*KDIM;

    const int n4 = (M_*KDIM + 3*KDIM*KDIM) / 4;
    cvt_all<<<(n4 + 255)/256, 256, 0, stream>>>(x, Wq, Wk, Wv, xb);

    proj_gemm_db<<<dim3(1536), 256, 0, stream>>>(xb, Wb, Qb, Kb, Vtb);
    flash_attn3<<<dim3(BH_*16), 256, 0, stream>>>(Qb, Kb, Vtb, out);
}